// Round 4
// baseline (28.687 us; speedup 1.0000x reference)
//
#include <hip/hip_runtime.h>
#include <math.h>

// Geometry (fixed): 256 x 8192 x 3 f32 per input = 2,097,152 rows of 3.
#define N_ROWS   (256 * 8192)
#define BLOCK    256
#define ROWS_PER_THREAD 8
#define GRID     (N_ROWS / (BLOCK * ROWS_PER_THREAD))   // 1024
#define F4_PER_THREAD 6                                 // 6 float4 = 8 rows

// Branchless acos, |err| < 6.8e-5 rad (Abramowitz-Stegun 4.4.45).
__device__ __forceinline__ float acos_fast(float x) {
    float ax = fabsf(x);
    float s  = sqrtf(fmaxf(0.0f, 1.0f - ax));
    float p  = fmaf(ax, -0.0187293f, 0.0742610f);
    p = fmaf(ax, p, -0.2121144f);
    p = fmaf(ax, p, 1.5707288f);
    float r = s * p;
    return (x >= 0.0f) ? r : (3.14159265358979f - r);
}

// Process 3 float4 (= 4 rows of 3 floats) from each input, return sum of angles.
__device__ __forceinline__ float rows4(float4 a0, float4 a1, float4 a2,
                                       float4 b0, float4 b1, float4 b2) {
    float ox[4] = {a0.x, a0.w, a1.z, a2.y};
    float oy[4] = {a0.y, a1.x, a1.w, a2.z};
    float oz[4] = {a0.z, a1.y, a2.x, a2.w};
    float txv[4] = {b0.x, b0.w, b1.z, b2.y};
    float tyv[4] = {b0.y, b1.x, b1.w, b2.z};
    float tzv[4] = {b0.z, b1.y, b2.x, b2.w};
    float s = 0.0f;
#pragma unroll
    for (int r = 0; r < 4; ++r) {
        float dot = ox[r] * txv[r] + oy[r] * tyv[r] + oz[r] * tzv[r];
        float no2 = ox[r] * ox[r] + oy[r] * oy[r] + oz[r] * oz[r];
        float nt2 = txv[r] * txv[r] + tyv[r] * tyv[r] + tzv[r] * tzv[r];
        float c = dot * rsqrtf(no2) * rsqrtf(nt2);
        c = fminf(1.0f, fmaxf(-1.0f, c));
        s += acos_fast(c);
    }
    return s;
}

__global__ __launch_bounds__(BLOCK) void angle_main(
    const float* __restrict__ o,
    const float* __restrict__ t,
    float* __restrict__ out)
{
    const int tx  = threadIdx.x;
    const int gid = blockIdx.x * BLOCK + tx;
    const long base4 = (long)gid * F4_PER_THREAD;
    const float4* o4 = reinterpret_cast<const float4*>(o);
    const float4* t4 = reinterpret_cast<const float4*>(t);

    // 12 independent float4 loads issued up front (192 B in flight/thread).
    float4 a0 = o4[base4 + 0];
    float4 a1 = o4[base4 + 1];
    float4 a2 = o4[base4 + 2];
    float4 a3 = o4[base4 + 3];
    float4 a4 = o4[base4 + 4];
    float4 a5 = o4[base4 + 5];
    float4 b0 = t4[base4 + 0];
    float4 b1 = t4[base4 + 1];
    float4 b2 = t4[base4 + 2];
    float4 b3 = t4[base4 + 3];
    float4 b4 = t4[base4 + 4];
    float4 b5 = t4[base4 + 5];

    float s = rows4(a0, a1, a2, b0, b1, b2)
            + rows4(a3, a4, a5, b3, b4, b5);

    // Wave (64) reduce, then block reduce via 4-entry LDS.
#pragma unroll
    for (int off = 32; off > 0; off >>= 1)
        s += __shfl_down(s, off, 64);

    __shared__ float waves[BLOCK / 64];
    const int lane = tx & 63;
    const int wid  = tx >> 6;
    if (lane == 0) waves[wid] = s;
    __syncthreads();

    if (tx == 0) {
        float bs = 0.0f;
#pragma unroll
        for (int w = 0; w < BLOCK / 64; ++w) bs += waves[w];
        // One hardware f32 atomic per block (1024 total), relaxed, agent
        // scope -- no fences, no L2 writeback. d_out is re-zeroed by the
        // memset node on every replay, so no cross-replay accumulation.
        __hip_atomic_fetch_add(out, bs * (1.0f / (float)N_ROWS),
                               __ATOMIC_RELAXED, __HIP_MEMORY_SCOPE_AGENT);
    }
}

extern "C" void kernel_launch(void* const* d_in, const int* in_sizes, int n_in,
                              void* d_out, int out_size, void* d_ws, size_t ws_size,
                              hipStream_t stream)
{
    const float* outputs = (const float*)d_in[0];
    const float* targets = (const float*)d_in[1];
    float* out = (float*)d_out;

    hipMemsetAsync(out, 0, sizeof(float), stream);  // graph-capturable node
    angle_main<<<GRID, BLOCK, 0, stream>>>(outputs, targets, out);
}